// Round 6
// baseline (12045.049 us; speedup 1.0000x reference)
//
#include <hip/hip_runtime.h>
#include <hip/hip_bf16.h>

// GumbelSoftmaxTokenizer: B=8, P=16384, FEAT=6, TOK=768, MT=128, K=16, IH=256
// All inputs float32; output buffer float32 (tokens, cents, masks concat).
#define NPT   131072      // B*P
#define BATCH 8
#define PPE   16384
#define MT    128
#define KNN   16
#define TOKD  768

// ---------------------------------------------------------------------------
// L1: h1[r] = relu(features[row(r)] @ w1(6x256) + b1); row = base+r or
// gather[r] (clamped) for the KNN-recompute pass.
// ---------------------------------------------------------------------------
__global__ __launch_bounds__(256) void l1_kernel(const float* __restrict__ f,
                                                 const float* __restrict__ w1,
                                                 const float* __restrict__ b1,
                                                 float* __restrict__ h1,
                                                 int base,
                                                 const int* __restrict__ gather)
{
    const int r = blockIdx.x, n = threadIdx.x;
    int row = gather ? gather[r] : (base + r);
    row = (row < 0) ? 0 : ((row >= NPT) ? (NPT - 1) : row);
    __shared__ float fs[6];
    if (threadIdx.x < 6) fs[threadIdx.x] = f[(long)row * 6 + threadIdx.x];
    __syncthreads();
    float acc = b1[n];
#pragma unroll
    for (int k = 0; k < 6; ++k) acc += fs[k] * w1[k * 256 + n];
    h1[(long)r * 256 + n] = fmaxf(acc, 0.f);
}

// ---------------------------------------------------------------------------
// fp32 GEMM: C(MxN) = [relu]( A(MxK) @ W(KxN) + bias ). Columns K1..K-1 of A
// come from coords[:,1:5] rows (a2base+r) when A2c != nullptr (concat for
// iw1). 64x64 tile, BK=16, 256 threads, 4x4 micro-tile. K guarded.
// ---------------------------------------------------------------------------
__global__ __launch_bounds__(256) void gemm_f32(
    const float* __restrict__ A, int lda, int K, int K1,
    const float* __restrict__ A2c, int a2base,
    const float* __restrict__ W, const float* __restrict__ bias,
    float* __restrict__ C, int N, int relu)
{
    __shared__ float As[16][65];
    __shared__ float Ws[16][64];
    const int tid  = threadIdx.x;
    const int row0 = blockIdx.y << 6, col0 = blockIdx.x << 6;
    const int tx = tid & 15, ty = tid >> 4;
    const int ak = tid & 15, am0 = tid >> 4;
    const int wn = tid & 63, wk0 = tid >> 6;
    float acc[4][4] = {{0.f}};
    const int ntiles = (K + 15) >> 4;
    for (int t = 0; t < ntiles; ++t) {
        const int k0 = t << 4;
        const int kgA = k0 + ak;
#pragma unroll
        for (int i = 0; i < 4; ++i) {
            const int r = row0 + am0 + (i << 4);
            float v = 0.f;
            if (kgA < K1)      v = A[(long)r * lda + kgA];
            else if (kgA < K)  v = A2c[(long)(a2base + r) * 5 + 1 + (kgA - K1)];
            As[ak][am0 + (i << 4)] = v;
        }
#pragma unroll
        for (int i = 0; i < 4; ++i) {
            const int kg = k0 + wk0 + (i << 2);
            Ws[wk0 + (i << 2)][wn] = (kg < K) ? W[(long)kg * N + col0 + wn] : 0.f;
        }
        __syncthreads();
#pragma unroll
        for (int kk = 0; kk < 16; ++kk) {
            float a[4], b[4];
#pragma unroll
            for (int i = 0; i < 4; ++i) a[i] = As[kk][(ty << 2) + i];
#pragma unroll
            for (int j = 0; j < 4; ++j) b[j] = Ws[kk][(tx << 2) + j];
#pragma unroll
            for (int i = 0; i < 4; ++i)
#pragma unroll
                for (int j = 0; j < 4; ++j)
                    acc[i][j] += a[i] * b[j];
        }
        __syncthreads();
    }
#pragma unroll
    for (int i = 0; i < 4; ++i) {
        const int r = row0 + (ty << 2) + i;
        const int c = col0 + (tx << 2);
        float4 v;
        v.x = acc[i][0] + bias[c + 0];
        v.y = acc[i][1] + bias[c + 1];
        v.z = acc[i][2] + bias[c + 2];
        v.w = acc[i][3] + bias[c + 3];
        if (relu) {
            v.x = fmaxf(v.x, 0.f); v.y = fmaxf(v.y, 0.f);
            v.z = fmaxf(v.z, 0.f); v.w = fmaxf(v.w, 0.f);
        }
        *(float4*)(&C[(long)r * N + c]) = v;
    }
}

// ---------------------------------------------------------------------------
// LayerNorm (in place) over 256 features/row
// ---------------------------------------------------------------------------
__global__ __launch_bounds__(256) void ln_kernel(float* __restrict__ z,
                                                 const float* __restrict__ g,
                                                 const float* __restrict__ b)
{
    const int r = blockIdx.x, tid = threadIdx.x;
    float x = z[(long)r * 256 + tid];
    __shared__ float part[4];
    __shared__ float mu_s, den_s;
    float s = x;
#pragma unroll
    for (int off = 32; off; off >>= 1) s += __shfl_down(s, off);
    if ((tid & 63) == 0) part[tid >> 6] = s;
    __syncthreads();
    if (tid == 0) mu_s = (part[0] + part[1] + part[2] + part[3]) * (1.f / 256.f);
    __syncthreads();
    const float mu = mu_s;
    const float d = x - mu;
    float s2 = d * d;
#pragma unroll
    for (int off = 32; off; off >>= 1) s2 += __shfl_down(s2, off);
    if ((tid & 63) == 0) part[tid >> 6] = s2;
    __syncthreads();
    if (tid == 0)
        den_s = sqrtf((part[0] + part[1] + part[2] + part[3]) * (1.f / 256.f) + 1e-5f);
    __syncthreads();
    z[(long)r * 256 + tid] = d / den_s * g[tid] + b[tid];
}

// ---------------------------------------------------------------------------
// imp = z2 @ iw3 + ib3 ; pert = (imp + noise)/max(exp(lt),0.1)
// ---------------------------------------------------------------------------
__global__ __launch_bounds__(256) void imp_kernel(const float* __restrict__ z2,
                                                  const float* __restrict__ iw3,
                                                  const float* __restrict__ ib3,
                                                  const float* __restrict__ noise,
                                                  const float* __restrict__ lt,
                                                  float* __restrict__ pert,
                                                  int base)
{
    const int r = blockIdx.x, tid = threadIdx.x;
    float v = z2[(long)r * 256 + tid] * iw3[tid];
    __shared__ float part[4];
#pragma unroll
    for (int off = 32; off; off >>= 1) v += __shfl_down(v, off);
    if ((tid & 63) == 0) part[tid >> 6] = v;
    __syncthreads();
    if (tid == 0) {
        const float imp  = part[0] + part[1] + part[2] + part[3] + ib3[0];
        const float temp = fmaxf(expf(lt[0]), 0.1f);
        pert[base + r] = (imp + noise[base + r]) / temp;
    }
}

// ---------------------------------------------------------------------------
// top-128 per event (desc pert, ties -> lower index). 256 threads, 64 vals
// per thread, cached per-thread segment max; only the losing thread rescans.
// Winning index clamped before any dependent access (NaN-proof).
// ---------------------------------------------------------------------------
__global__ __launch_bounds__(256) void topk_kernel(const float* __restrict__ pert,
                                                   const float* __restrict__ coords,
                                                   float* __restrict__ centf)
{
    const int e = blockIdx.x, tid = threadIdx.x;
    const int base = e * PPE;
    float v[64];
#pragma unroll
    for (int i = 0; i < 64; ++i) v[i] = pert[base + i * 256 + tid];
    float mx = -3.4e38f; int mp = 0x7FFFFFFF;
#pragma unroll
    for (int i = 0; i < 64; ++i) {
        const float val = v[i]; const int p = i * 256 + tid;
        if (val > mx || (val == mx && p < mp)) { mx = val; mp = p; }
    }
    __shared__ float wv[4];
    __shared__ int   wp[4];
    __shared__ int   bestp_s;
    for (int round = 0; round < MT; ++round) {
        float bv = mx; int bp = mp;
#pragma unroll
        for (int off = 32; off; off >>= 1) {
            const float ov = __shfl_down(bv, off);
            const int   op = __shfl_down(bp, off);
            if (ov > bv || (ov == bv && op < bp)) { bv = ov; bp = op; }
        }
        if ((tid & 63) == 0) { wv[tid >> 6] = bv; wp[tid >> 6] = bp; }
        __syncthreads();
        if (tid == 0) {
            float Bv = wv[0]; int Bp = wp[0];
#pragma unroll
            for (int i = 1; i < 4; ++i)
                if (wv[i] > Bv || (wv[i] == Bv && wp[i] < Bp)) { Bv = wv[i]; Bp = wp[i]; }
            Bp = (Bp < 0) ? 0 : ((Bp >= PPE) ? (PPE - 1) : Bp);   // NaN-proof clamp
            bestp_s = Bp;
            const long cb = (long)(base + Bp) * 5;
            centf[(long)(e * MT + round) * 4 + 0] = coords[cb + 1];
            centf[(long)(e * MT + round) * 4 + 1] = coords[cb + 2];
            centf[(long)(e * MT + round) * 4 + 2] = coords[cb + 3];
            centf[(long)(e * MT + round) * 4 + 3] = coords[cb + 4];
        }
        __syncthreads();
        const int Bp = bestp_s;
        if ((Bp & 255) == tid) {
            v[Bp >> 8] = -3.4e38f;
            mx = -3.4e38f; mp = 0x7FFFFFFF;
#pragma unroll
            for (int i = 0; i < 64; ++i) {
                const float val = v[i]; const int p = i * 256 + tid;
                if (val > mx || (val == mx && p < mp)) { mx = val; mp = p; }
            }
        }
    }
}

// ---------------------------------------------------------------------------
// per (event,centroid): 16-NN over 16384 points (smallest d2, ties -> lower
// index = jax top_k(-d2)). Sequential 4-term fp32 sum matches the np ref.
// ---------------------------------------------------------------------------
__global__ __launch_bounds__(256) void knn_kernel(const float* __restrict__ coords,
                                                  const float* __restrict__ centf,
                                                  int* __restrict__ knn_idx)
{
    const int blk = blockIdx.x;           // e*128 + m
    const int e = blk >> 7;
    const int tid = threadIdx.x;
    const int base = e * PPE;
    const float c0 = centf[(long)blk * 4 + 0];
    const float c1 = centf[(long)blk * 4 + 1];
    const float c2 = centf[(long)blk * 4 + 2];
    const float c3 = centf[(long)blk * 4 + 3];
    float ld[KNN]; int li[KNN];
#pragma unroll
    for (int i = 0; i < KNN; ++i) { ld[i] = 3.4e38f; li[i] = 0x7FFFFFFF; }
    for (int p = tid; p < PPE; p += 256) {
        const long cb = (long)(base + p) * 5;
        const float x0 = coords[cb + 1];
        const float x1 = coords[cb + 2];
        const float x2 = coords[cb + 3];
        const float x3 = coords[cb + 4];
        const float q0 = __fmul_rn(c0 - x0, c0 - x0);
        const float q1 = __fmul_rn(c1 - x1, c1 - x1);
        const float q2 = __fmul_rn(c2 - x2, c2 - x2);
        const float q3 = __fmul_rn(c3 - x3, c3 - x3);
        const float d  = __fadd_rn(__fadd_rn(__fadd_rn(q0, q1), q2), q3);
        if (d < ld[KNN - 1] || (d == ld[KNN - 1] && p < li[KNN - 1])) {
            int j = KNN - 1;
            while (j > 0 && (d < ld[j - 1] || (d == ld[j - 1] && p < li[j - 1]))) {
                ld[j] = ld[j - 1]; li[j] = li[j - 1]; --j;
            }
            ld[j] = d; li[j] = p;
        }
    }
    __shared__ float hv[256];
    __shared__ int   hi[256];
    __shared__ int   ho[256];
    int ptr = 0;
    for (int r = 0; r < KNN; ++r) {
        hv[tid] = (ptr < KNN) ? ld[ptr] : 3.4e38f;
        hi[tid] = (ptr < KNN) ? li[ptr] : 0x7FFFFFFF;
        ho[tid] = tid;
        __syncthreads();
        for (int s = 128; s > 0; s >>= 1) {
            if (tid < s) {
                const float v2 = hv[tid + s]; const int i2 = hi[tid + s];
                if (v2 < hv[tid] || (v2 == hv[tid] && i2 < hi[tid])) {
                    hv[tid] = v2; hi[tid] = i2; ho[tid] = ho[tid + s];
                }
            }
            __syncthreads();
        }
        if (tid == ho[0]) ptr++;
        if (tid == 0) {
            int ix = hi[0];
            ix = (ix < 0) ? 0 : ((ix >= PPE) ? (PPE - 1) : ix);   // NaN-proof
            knn_idx[blk * KNN + r] = base + ix;
        }
        __syncthreads();
    }
}

// ---------------------------------------------------------------------------
// pooled[blk][t] = max over 16 recomputed-pf neighbor rows (chunk layout)
// ---------------------------------------------------------------------------
__global__ __launch_bounds__(256) void pool_kernel(const float* __restrict__ pf_nbr,
                                                   float* __restrict__ pooled)
{
    const int blk = blockIdx.x, tid = threadIdx.x;
    for (int t = tid; t < TOKD; t += 256) {
        float mx = -3.4e38f;
#pragma unroll
        for (int j = 0; j < KNN; ++j)
            mx = fmaxf(mx, pf_nbr[(long)(blk * KNN + j) * TOKD + t]);
        pooled[(long)blk * TOKD + t] = mx;
    }
}

// ---------------------------------------------------------------------------
// per event: stable rank by cent[:,3] asc + emit tokens/cents/masks as FP32.
// Every d_out write guarded by out_size.
// ---------------------------------------------------------------------------
__global__ __launch_bounds__(256) void emit_kernel(const float* __restrict__ centf,
                                                   const float* __restrict__ tokf_e,
                                                   int e, float* __restrict__ out,
                                                   long out_size)
{
    const int tid = threadIdx.x;
    __shared__ float tv[MT];
    __shared__ int   rk[MT];
    if (tid < MT) tv[tid] = centf[(long)(e * MT + tid) * 4 + 3];
    __syncthreads();
    if (tid < MT) {
        const float t = tv[tid]; int r = 0;
        for (int j = 0; j < MT; ++j)
            r += (tv[j] < t || (tv[j] == t && j < tid)) ? 1 : 0;
        rk[tid] = r;
    }
    __syncthreads();
    const long cent_off = (long)BATCH * MT * TOKD;         // 786432
    const long mask_off = cent_off + (long)BATCH * MT * 4; // 790528
    for (int idx = tid; idx < MT * TOKD; idx += 256) {
        const int i = idx / TOKD, t = idx % TOKD;
        const long g = ((long)e * MT + rk[i]) * TOKD + t;
        if (g < out_size)
            out[g] = tokf_e[(long)i * TOKD + t];
    }
    for (int idx = tid; idx < MT * 4; idx += 256) {
        const int i = idx >> 2, d = idx & 3;
        const long g = cent_off + ((long)e * MT + rk[i]) * 4 + d;
        if (g < out_size)
            out[g] = centf[((long)e * MT + i) * 4 + d];
    }
    for (int idx = tid; idx < MT; idx += 256) {
        const long g = mask_off + (long)e * MT + idx;
        if (g < out_size)
            out[g] = 1.0f;
    }
}

// ---------------------------------------------------------------------------
extern "C" void kernel_launch(void* const* d_in, const int* in_sizes, int n_in,
                              void* d_out, int out_size, void* d_ws, size_t ws_size,
                              hipStream_t stream)
{
    const float* coords = (const float*)d_in[0];
    const float* feats  = (const float*)d_in[1];
    const float* lt     = (const float*)d_in[2];
    const float* w1  = (const float*)d_in[3];  const float* b1  = (const float*)d_in[4];
    const float* w2  = (const float*)d_in[5];  const float* b2  = (const float*)d_in[6];
    const float* w3  = (const float*)d_in[7];  const float* b3  = (const float*)d_in[8];
    const float* w4  = (const float*)d_in[9];  const float* b4  = (const float*)d_in[10];
    const float* iw1 = (const float*)d_in[11]; const float* ib1 = (const float*)d_in[12];
    const float* lng = (const float*)d_in[13]; const float* lnb = (const float*)d_in[14];
    const float* iw2 = (const float*)d_in[15]; const float* ib2 = (const float*)d_in[16];
    const float* iw3 = (const float*)d_in[17]; const float* ib3 = (const float*)d_in[18];
    const float* nw1 = (const float*)d_in[19]; const float* nb1 = (const float*)d_in[20];
    const float* nw2 = (const float*)d_in[21]; const float* nb2 = (const float*)d_in[22];
    const float* noise = (const float*)d_in[23];

    // fixed ws part (floats): pert + centf + knn + pooled ≈ 3.7 MB
    const size_t FIXED = (size_t)NPT + 4096 + 16384 + (size_t)1024 * TOKD;
    const size_t perrow = 256 + 512 + 768 + 768 + 256 + 256;   // 2816 fl/row
    int ch = 128;   // floor: total ~5.2 MB
    while (ch < PPE && (FIXED + (size_t)(ch * 2) * perrow) * 4 <= ws_size) ch <<= 1;

    float* pert   = (float*)d_ws;                       // NPT
    float* centf  = pert + NPT;                         // 1024*4
    int*   knn    = (int*)(centf + 4096);               // 16384 ints
    float* pooled = (float*)(knn + 16384);              // 1024*768
    float* region = pooled + (size_t)1024 * TOKD;       // ch*2816 floats
    float* bh1 = region;
    float* bh2 = bh1 + (size_t)ch * 256;
    float* bh3 = bh2 + (size_t)ch * 512;
    float* bpf = bh3 + (size_t)ch * 768;
    float* bz1 = bpf + (size_t)ch * 768;
    float* bz2 = bz1 + (size_t)ch * 256;
    // token-MLP overlay of the chunk region (used after chunk loops finish):
    float* t1   = region;                               // 128*768
    float* tokf = region + (size_t)MT * TOKD;           // 128*768

    // ---- chunked MLP: features -> pert (selection chain, fp32) ----
    for (int ck = 0; ck < NPT / ch; ++ck) {
        const int base = ck * ch;
        l1_kernel<<<dim3(ch), dim3(256), 0, stream>>>(feats, w1, b1, bh1, base, nullptr);
        gemm_f32<<<dim3(512 / 64, ch / 64), dim3(256), 0, stream>>>(
            bh1, 256, 256, 256, nullptr, 0, w2, b2, bh2, 512, 1);
        gemm_f32<<<dim3(768 / 64, ch / 64), dim3(256), 0, stream>>>(
            bh2, 512, 512, 512, nullptr, 0, w3, b3, bh3, 768, 1);
        gemm_f32<<<dim3(768 / 64, ch / 64), dim3(256), 0, stream>>>(
            bh3, 768, 768, 768, nullptr, 0, w4, b4, bpf, 768, 0);
        gemm_f32<<<dim3(256 / 64, ch / 64), dim3(256), 0, stream>>>(
            bpf, 768, 772, 768, coords, base, iw1, ib1, bz1, 256, 1);
        ln_kernel<<<dim3(ch), dim3(256), 0, stream>>>(bz1, lng, lnb);
        gemm_f32<<<dim3(256 / 64, ch / 64), dim3(256), 0, stream>>>(
            bz1, 256, 256, 256, nullptr, 0, iw2, ib2, bz2, 256, 1);
        imp_kernel<<<dim3(ch), dim3(256), 0, stream>>>(bz2, iw3, ib3, noise, lt, pert, base);
    }

    // ---- selection + KNN ----
    topk_kernel<<<dim3(BATCH), dim3(256), 0, stream>>>(pert, coords, centf);
    knn_kernel<<<dim3(BATCH * MT), dim3(256), 0, stream>>>(coords, centf, knn);

    // ---- recompute pf for the 16384 gathered neighbor rows (chunked), pool ----
    const int NBR = BATCH * MT * KNN;   // 16384
    for (int rc = 0; rc < NBR / ch; ++rc) {
        l1_kernel<<<dim3(ch), dim3(256), 0, stream>>>(feats, w1, b1, bh1, 0, knn + (size_t)rc * ch);
        gemm_f32<<<dim3(512 / 64, ch / 64), dim3(256), 0, stream>>>(
            bh1, 256, 256, 256, nullptr, 0, w2, b2, bh2, 512, 1);
        gemm_f32<<<dim3(768 / 64, ch / 64), dim3(256), 0, stream>>>(
            bh2, 512, 512, 512, nullptr, 0, w3, b3, bh3, 768, 1);
        gemm_f32<<<dim3(768 / 64, ch / 64), dim3(256), 0, stream>>>(
            bh3, 768, 768, 768, nullptr, 0, w4, b4, bpf, 768, 0);
        pool_kernel<<<dim3(ch / KNN), dim3(256), 0, stream>>>(
            bpf, pooled + (size_t)rc * (ch / KNN) * TOKD);
    }

    // ---- token MLP + emit, per event (region reused as t1/tokf) ----
    for (int e = 0; e < BATCH; ++e) {
        gemm_f32<<<dim3(768 / 64, MT / 64), dim3(256), 0, stream>>>(
            pooled + (size_t)e * MT * TOKD, 768, 768, 768, nullptr, 0,
            nw1, nb1, t1, 768, 1);
        gemm_f32<<<dim3(768 / 64, MT / 64), dim3(256), 0, stream>>>(
            t1, 768, 768, 768, nullptr, 0, nw2, nb2, tokf, 768, 0);
        emit_kernel<<<dim3(1), dim3(256), 0, stream>>>(
            centf, tokf, e, (float*)d_out, (long)out_size);
    }
}

// Round 7
// 7608.763 us; speedup vs baseline: 1.5830x; 1.5830x over previous
//
#include <hip/hip_runtime.h>
#include <hip/hip_bf16.h>

// GumbelSoftmaxTokenizer: B=8, P=16384, FEAT=6, TOK=768, MT=128, K=16, IH=256
// All inputs float32; output buffer float32 (tokens, cents, masks concat).
#define NPT   131072      // B*P
#define BATCH 8
#define PPE   16384
#define MT    128
#define KNN   16
#define TOKD  768

// ---------------------------------------------------------------------------
// L1: h1[r] = relu(features[row(r)] @ w1(6x256) + b1); row = base+r or
// gather[r] (clamped) for the KNN-recompute pass.
// ---------------------------------------------------------------------------
__global__ __launch_bounds__(256) void l1_kernel(const float* __restrict__ f,
                                                 const float* __restrict__ w1,
                                                 const float* __restrict__ b1,
                                                 float* __restrict__ h1,
                                                 int base,
                                                 const int* __restrict__ gather)
{
    const int r = blockIdx.x, n = threadIdx.x;
    int row = gather ? gather[r] : (base + r);
    row = (row < 0) ? 0 : ((row >= NPT) ? (NPT - 1) : row);
    __shared__ float fs[6];
    if (threadIdx.x < 6) fs[threadIdx.x] = f[(long)row * 6 + threadIdx.x];
    __syncthreads();
    float acc = b1[n];
#pragma unroll
    for (int k = 0; k < 6; ++k) acc += fs[k] * w1[k * 256 + n];
    h1[(long)r * 256 + n] = fmaxf(acc, 0.f);
}

// ---------------------------------------------------------------------------
// fp32 GEMM: C(MxN) = [relu]( A(MxK) @ W(KxN) + bias ). Columns K1..K-1 of A
// come from coords[:,1:5] rows (a2base+r) when K>K1 (concat for iw1).
// 64x64 tile, BK=16, 256 threads, 4x4 micro-tile. float4 global loads;
// As padded to 68 (272B rows = 16B-aligned) so LDS reads are ds_read_b128.
// Accumulation order identical to the scalar version (numerics unchanged).
// ---------------------------------------------------------------------------
__global__ __launch_bounds__(256) void gemm_f32(
    const float* __restrict__ A, int lda, int K, int K1,
    const float* __restrict__ A2c, int a2base,
    const float* __restrict__ W, const float* __restrict__ bias,
    float* __restrict__ C, int N, int relu)
{
    __shared__ float As[16][68];   // [k][m], row stride 272B (17*16) -> b128 ok
    __shared__ float Ws[16][64];
    const int tid  = threadIdx.x;
    const int row0 = blockIdx.y << 6, col0 = blockIdx.x << 6;
    const int tx = tid & 15, ty = tid >> 4;
    const int am  = tid >> 2,  ak4 = (tid & 3) << 2;    // A loader: row, k*4
    const int wk  = tid >> 4,  wn4 = (tid & 15) << 2;   // W loader: k, n*4
    float acc[4][4] = {{0.f}};
    const int ntiles = (K + 15) >> 4;
    for (int t = 0; t < ntiles; ++t) {
        const int k0 = t << 4;
        // ---- A tile: 64 rows x 16 k, one float4 per thread
        {
            const int kg = k0 + ak4;
            const int r  = row0 + am;
            float4 v;
            if (kg + 3 < K1) {
                v = *(const float4*)&A[(long)r * lda + kg];
            } else {
                float tmp[4];
#pragma unroll
                for (int q = 0; q < 4; ++q) {
                    const int kq = kg + q;
                    float x = 0.f;
                    if (kq < K1)     x = A[(long)r * lda + kq];
                    else if (kq < K) x = A2c[(long)(a2base + r) * 5 + 1 + (kq - K1)];
                    tmp[q] = x;
                }
                v = make_float4(tmp[0], tmp[1], tmp[2], tmp[3]);
            }
            As[ak4 + 0][am] = v.x;
            As[ak4 + 1][am] = v.y;
            As[ak4 + 2][am] = v.z;
            As[ak4 + 3][am] = v.w;
        }
        // ---- W tile: 16 k x 64 n, one float4 per thread
        {
            const int kg = k0 + wk;
            float4 v = make_float4(0.f, 0.f, 0.f, 0.f);
            if (kg < K) v = *(const float4*)&W[(long)kg * N + col0 + wn4];
            *(float4*)&Ws[wk][wn4] = v;
        }
        __syncthreads();
#pragma unroll
        for (int kk = 0; kk < 16; ++kk) {
            const float4 a4 = *(const float4*)&As[kk][ty << 2];
            const float4 b4 = *(const float4*)&Ws[kk][tx << 2];
            const float a[4] = {a4.x, a4.y, a4.z, a4.w};
            const float b[4] = {b4.x, b4.y, b4.z, b4.w};
#pragma unroll
            for (int i = 0; i < 4; ++i)
#pragma unroll
                for (int j = 0; j < 4; ++j)
                    acc[i][j] += a[i] * b[j];
        }
        __syncthreads();
    }
#pragma unroll
    for (int i = 0; i < 4; ++i) {
        const int r = row0 + (ty << 2) + i;
        const int c = col0 + (tx << 2);
        float4 v;
        v.x = acc[i][0] + bias[c + 0];
        v.y = acc[i][1] + bias[c + 1];
        v.z = acc[i][2] + bias[c + 2];
        v.w = acc[i][3] + bias[c + 3];
        if (relu) {
            v.x = fmaxf(v.x, 0.f); v.y = fmaxf(v.y, 0.f);
            v.z = fmaxf(v.z, 0.f); v.w = fmaxf(v.w, 0.f);
        }
        *(float4*)(&C[(long)r * N + c]) = v;
    }
}

// ---------------------------------------------------------------------------
// LayerNorm (in place) over 256 features/row
// ---------------------------------------------------------------------------
__global__ __launch_bounds__(256) void ln_kernel(float* __restrict__ z,
                                                 const float* __restrict__ g,
                                                 const float* __restrict__ b)
{
    const int r = blockIdx.x, tid = threadIdx.x;
    float x = z[(long)r * 256 + tid];
    __shared__ float part[4];
    __shared__ float mu_s, den_s;
    float s = x;
#pragma unroll
    for (int off = 32; off; off >>= 1) s += __shfl_down(s, off);
    if ((tid & 63) == 0) part[tid >> 6] = s;
    __syncthreads();
    if (tid == 0) mu_s = (part[0] + part[1] + part[2] + part[3]) * (1.f / 256.f);
    __syncthreads();
    const float mu = mu_s;
    const float d = x - mu;
    float s2 = d * d;
#pragma unroll
    for (int off = 32; off; off >>= 1) s2 += __shfl_down(s2, off);
    if ((tid & 63) == 0) part[tid >> 6] = s2;
    __syncthreads();
    if (tid == 0)
        den_s = sqrtf((part[0] + part[1] + part[2] + part[3]) * (1.f / 256.f) + 1e-5f);
    __syncthreads();
    z[(long)r * 256 + tid] = d / den_s * g[tid] + b[tid];
}

// ---------------------------------------------------------------------------
// imp = z2 @ iw3 + ib3 ; pert = (imp + noise)/max(exp(lt),0.1)
// ---------------------------------------------------------------------------
__global__ __launch_bounds__(256) void imp_kernel(const float* __restrict__ z2,
                                                  const float* __restrict__ iw3,
                                                  const float* __restrict__ ib3,
                                                  const float* __restrict__ noise,
                                                  const float* __restrict__ lt,
                                                  float* __restrict__ pert,
                                                  int base)
{
    const int r = blockIdx.x, tid = threadIdx.x;
    float v = z2[(long)r * 256 + tid] * iw3[tid];
    __shared__ float part[4];
#pragma unroll
    for (int off = 32; off; off >>= 1) v += __shfl_down(v, off);
    if ((tid & 63) == 0) part[tid >> 6] = v;
    __syncthreads();
    if (tid == 0) {
        const float imp  = part[0] + part[1] + part[2] + part[3] + ib3[0];
        const float temp = fmaxf(expf(lt[0]), 0.1f);
        pert[base + r] = (imp + noise[base + r]) / temp;
    }
}

// ---------------------------------------------------------------------------
// top-128 per event via 4-pass radix-select on the order-preserving uint map
// (u > u' <=> f > f'), then exact tie handling (lowest indices first) and a
// 128-element bitonic sort by (value desc, index asc) = jax top_k order.
// ---------------------------------------------------------------------------
__device__ __forceinline__ unsigned fmap(float f) {
    unsigned x = __float_as_uint(f);
    return (x & 0x80000000u) ? ~x : (x | 0x80000000u);
}

__global__ __launch_bounds__(256) void topk_kernel(const float* __restrict__ pert,
                                                   const float* __restrict__ coords,
                                                   float* __restrict__ centf)
{
    const int e = blockIdx.x, tid = threadIdx.x;
    const int base = e * PPE;
    __shared__ unsigned hist[256];
    __shared__ unsigned sh_prefix;
    __shared__ int sh_need;
    unsigned prefix = 0, known = 0;
    int need = MT;
    for (int shift = 24; shift >= 0; shift -= 8) {
        hist[tid] = 0;
        __syncthreads();
        for (int i = tid; i < PPE; i += 256) {
            const unsigned u = fmap(pert[base + i]);
            if ((u & known) == prefix) atomicAdd(&hist[(u >> shift) & 255u], 1u);
        }
        __syncthreads();
        if (tid == 0) {
            int cum = 0, b = 255;
            for (; b > 0; --b) { cum += (int)hist[b]; if (cum >= need) break; }
            if (cum < need) { cum += (int)hist[0]; b = 0; }   // b==0 catch-all
            sh_need   = need - (cum - (int)hist[b]);
            sh_prefix = prefix | ((unsigned)b << shift);
        }
        __syncthreads();
        need   = sh_need;
        prefix = sh_prefix;
        known |= (255u << shift);
        __syncthreads();
    }
    const unsigned T = prefix;     // exact threshold
    const int need_eq = need;      // how many ==T to take (lowest index first)

    __shared__ unsigned selu[MT];
    __shared__ int      seli[MT];
    __shared__ int cgt, ceq;
    __shared__ int eqbuf[256];
    if (tid == 0) { cgt = 0; ceq = 0; }
    __syncthreads();
    for (int i = tid; i < PPE; i += 256) {
        const unsigned u = fmap(pert[base + i]);
        if (u > T)       { int p = atomicAdd(&cgt, 1); selu[p] = u; seli[p] = i; }
        else if (u == T) { int p = atomicAdd(&ceq, 1); if (p < 256) eqbuf[p] = i; }
    }
    __syncthreads();
    const int ngt = cgt;           // == MT - need_eq by construction
    if (ceq <= 256) {
        // sort equal-indices ascending (bitonic over 256 with +inf padding)
        if (tid >= ceq) eqbuf[tid] = 0x7FFFFFFF;
        __syncthreads();
        for (int k = 2; k <= 256; k <<= 1)
            for (int j = k >> 1; j > 0; j >>= 1) {
                const int l = tid ^ j;
                if (l > tid) {
                    const int a = eqbuf[tid], b = eqbuf[l];
                    const bool up = ((tid & k) == 0);       // ascending block
                    if (up ? (a > b) : (a < b)) { eqbuf[tid] = b; eqbuf[l] = a; }
                }
                __syncthreads();
            }
        if (tid < need_eq) { selu[ngt + tid] = T; seli[ngt + tid] = eqbuf[tid]; }
    } else if (tid == 0) {
        // pathological mass-tie fallback (effectively unreachable)
        int cur = -1;
        for (int q = 0; q < need_eq; ++q) {
            int best = 0x7FFFFFFF;
            for (int i = 0; i < PPE; ++i)
                if (i > cur && fmap(pert[base + i]) == T && i < best) best = i;
            selu[ngt + q] = T; seli[ngt + q] = best; cur = best;
        }
    }
    __syncthreads();
    // bitonic sort 128 items by (u desc, idx asc): 64-bit key, descending
    __shared__ unsigned long long key[MT];
    if (tid < MT)
        key[tid] = ((unsigned long long)selu[tid] << 32) | (unsigned)(~seli[tid]);
    __syncthreads();
    for (int k = 2; k <= MT; k <<= 1)
        for (int j = k >> 1; j > 0; j >>= 1) {
            if (tid < MT) {
                const int l = tid ^ j;
                if (l > tid) {
                    const unsigned long long a = key[tid], b = key[l];
                    const bool up = ((tid & k) == 0);       // descending block
                    if (up ? (a < b) : (a > b)) { key[tid] = b; key[l] = a; }
                }
            }
            __syncthreads();
        }
    if (tid < MT) {
        const int idx = (int)(~(unsigned)(key[tid] & 0xFFFFFFFFu));
        const long cb = (long)(base + idx) * 5;
        centf[(long)(e * MT + tid) * 4 + 0] = coords[cb + 1];
        centf[(long)(e * MT + tid) * 4 + 1] = coords[cb + 2];
        centf[(long)(e * MT + tid) * 4 + 2] = coords[cb + 3];
        centf[(long)(e * MT + tid) * 4 + 3] = coords[cb + 4];
    }
}

// ---------------------------------------------------------------------------
// per (event,centroid): 16-NN over 16384 points (smallest d2, ties -> lower
// index = jax top_k(-d2)). Sequential 4-term fp32 sum matches the np ref.
// ---------------------------------------------------------------------------
__global__ __launch_bounds__(256) void knn_kernel(const float* __restrict__ coords,
                                                  const float* __restrict__ centf,
                                                  int* __restrict__ knn_idx)
{
    const int blk = blockIdx.x;           // e*128 + m
    const int e = blk >> 7;
    const int tid = threadIdx.x;
    const int base = e * PPE;
    const float c0 = centf[(long)blk * 4 + 0];
    const float c1 = centf[(long)blk * 4 + 1];
    const float c2 = centf[(long)blk * 4 + 2];
    const float c3 = centf[(long)blk * 4 + 3];
    float ld[KNN]; int li[KNN];
#pragma unroll
    for (int i = 0; i < KNN; ++i) { ld[i] = 3.4e38f; li[i] = 0x7FFFFFFF; }
    for (int p = tid; p < PPE; p += 256) {
        const long cb = (long)(base + p) * 5;
        const float x0 = coords[cb + 1];
        const float x1 = coords[cb + 2];
        const float x2 = coords[cb + 3];
        const float x3 = coords[cb + 4];
        const float q0 = __fmul_rn(c0 - x0, c0 - x0);
        const float q1 = __fmul_rn(c1 - x1, c1 - x1);
        const float q2 = __fmul_rn(c2 - x2, c2 - x2);
        const float q3 = __fmul_rn(c3 - x3, c3 - x3);
        const float d  = __fadd_rn(__fadd_rn(__fadd_rn(q0, q1), q2), q3);
        if (d < ld[KNN - 1] || (d == ld[KNN - 1] && p < li[KNN - 1])) {
            int j = KNN - 1;
            while (j > 0 && (d < ld[j - 1] || (d == ld[j - 1] && p < li[j - 1]))) {
                ld[j] = ld[j - 1]; li[j] = li[j - 1]; --j;
            }
            ld[j] = d; li[j] = p;
        }
    }
    __shared__ float hv[256];
    __shared__ int   hi[256];
    __shared__ int   ho[256];
    int ptr = 0;
    for (int r = 0; r < KNN; ++r) {
        hv[tid] = (ptr < KNN) ? ld[ptr] : 3.4e38f;
        hi[tid] = (ptr < KNN) ? li[ptr] : 0x7FFFFFFF;
        ho[tid] = tid;
        __syncthreads();
        for (int s = 128; s > 0; s >>= 1) {
            if (tid < s) {
                const float v2 = hv[tid + s]; const int i2 = hi[tid + s];
                if (v2 < hv[tid] || (v2 == hv[tid] && i2 < hi[tid])) {
                    hv[tid] = v2; hi[tid] = i2; ho[tid] = ho[tid + s];
                }
            }
            __syncthreads();
        }
        if (tid == ho[0]) ptr++;
        if (tid == 0) {
            int ix = hi[0];
            ix = (ix < 0) ? 0 : ((ix >= PPE) ? (PPE - 1) : ix);
            knn_idx[blk * KNN + r] = base + ix;
        }
        __syncthreads();
    }
}

// ---------------------------------------------------------------------------
// pooled[blk][t] = max over 16 recomputed-pf neighbor rows (chunk layout)
// ---------------------------------------------------------------------------
__global__ __launch_bounds__(256) void pool_kernel(const float* __restrict__ pf_nbr,
                                                   float* __restrict__ pooled)
{
    const int blk = blockIdx.x, tid = threadIdx.x;
    for (int t = tid; t < TOKD; t += 256) {
        float mx = -3.4e38f;
#pragma unroll
        for (int j = 0; j < KNN; ++j)
            mx = fmaxf(mx, pf_nbr[(long)(blk * KNN + j) * TOKD + t]);
        pooled[(long)blk * TOKD + t] = mx;
    }
}

// ---------------------------------------------------------------------------
// per event: stable rank by cent[:,3] asc + emit tokens/cents/masks as FP32.
// ---------------------------------------------------------------------------
__global__ __launch_bounds__(256) void emit_kernel(const float* __restrict__ centf,
                                                   const float* __restrict__ tokf_e,
                                                   int e, float* __restrict__ out,
                                                   long out_size)
{
    const int tid = threadIdx.x;
    __shared__ float tv[MT];
    __shared__ int   rk[MT];
    if (tid < MT) tv[tid] = centf[(long)(e * MT + tid) * 4 + 3];
    __syncthreads();
    if (tid < MT) {
        const float t = tv[tid]; int r = 0;
        for (int j = 0; j < MT; ++j)
            r += (tv[j] < t || (tv[j] == t && j < tid)) ? 1 : 0;
        rk[tid] = r;
    }
    __syncthreads();
    const long cent_off = (long)BATCH * MT * TOKD;         // 786432
    const long mask_off = cent_off + (long)BATCH * MT * 4; // 790528
    for (int idx = tid; idx < MT * TOKD; idx += 256) {
        const int i = idx / TOKD, t = idx % TOKD;
        const long g = ((long)e * MT + rk[i]) * TOKD + t;
        if (g < out_size) out[g] = tokf_e[(long)i * TOKD + t];
    }
    for (int idx = tid; idx < MT * 4; idx += 256) {
        const int i = idx >> 2, d = idx & 3;
        const long g = cent_off + ((long)e * MT + rk[i]) * 4 + d;
        if (g < out_size) out[g] = centf[((long)e * MT + i) * 4 + d];
    }
    for (int idx = tid; idx < MT; idx += 256) {
        const long g = mask_off + (long)e * MT + idx;
        if (g < out_size) out[g] = 1.0f;
    }
}

// ---------------------------------------------------------------------------
extern "C" void kernel_launch(void* const* d_in, const int* in_sizes, int n_in,
                              void* d_out, int out_size, void* d_ws, size_t ws_size,
                              hipStream_t stream)
{
    const float* coords = (const float*)d_in[0];
    const float* feats  = (const float*)d_in[1];
    const float* lt     = (const float*)d_in[2];
    const float* w1  = (const float*)d_in[3];  const float* b1  = (const float*)d_in[4];
    const float* w2  = (const float*)d_in[5];  const float* b2  = (const float*)d_in[6];
    const float* w3  = (const float*)d_in[7];  const float* b3  = (const float*)d_in[8];
    const float* w4  = (const float*)d_in[9];  const float* b4  = (const float*)d_in[10];
    const float* iw1 = (const float*)d_in[11]; const float* ib1 = (const float*)d_in[12];
    const float* lng = (const float*)d_in[13]; const float* lnb = (const float*)d_in[14];
    const float* iw2 = (const float*)d_in[15]; const float* ib2 = (const float*)d_in[16];
    const float* iw3 = (const float*)d_in[17]; const float* ib3 = (const float*)d_in[18];
    const float* nw1 = (const float*)d_in[19]; const float* nb1 = (const float*)d_in[20];
    const float* nw2 = (const float*)d_in[21]; const float* nb2 = (const float*)d_in[22];
    const float* noise = (const float*)d_in[23];

    // fixed ws (floats): pert + centf + knn + pooled = 937,984 (~3.75 MB)
    // ping-pong region: 2 x ch x 768 floats (activation chain max width 768)
    const size_t FIXED  = (size_t)NPT + 4096 + 16384 + (size_t)1024 * TOKD;
    const size_t perrow = 1536;
    int ch = 128;
    while (ch < PPE && (FIXED + (size_t)(ch * 2) * perrow) * 4 <= ws_size) ch <<= 1;

    float* pert   = (float*)d_ws;                       // NPT
    float* centf  = pert + NPT;                         // 1024*4
    int*   knn    = (int*)(centf + 4096);               // 16384 ints
    float* pooled = (float*)(knn + 16384);              // 1024*768
    float* bufA   = pooled + (size_t)1024 * TOKD;       // ch*768
    float* bufB   = bufA + (size_t)ch * 768;            // ch*768

    // ---- chunked MLP: features -> pert (selection chain, fp32) ----
    // chain: A=h1(256) -> B=h2(512) -> A=h3(768) -> B=pf(768) -> A=z1(256)
    //        -> ln(A) -> B=z2(256) -> pert
    for (int ck = 0; ck < NPT / ch; ++ck) {
        const int base = ck * ch;
        l1_kernel<<<dim3(ch), dim3(256), 0, stream>>>(feats, w1, b1, bufA, base, nullptr);
        gemm_f32<<<dim3(512 / 64, ch / 64), dim3(256), 0, stream>>>(
            bufA, 256, 256, 256, nullptr, 0, w2, b2, bufB, 512, 1);
        gemm_f32<<<dim3(768 / 64, ch / 64), dim3(256), 0, stream>>>(
            bufB, 512, 512, 512, nullptr, 0, w3, b3, bufA, 768, 1);
        gemm_f32<<<dim3(768 / 64, ch / 64), dim3(256), 0, stream>>>(
            bufA, 768, 768, 768, nullptr, 0, w4, b4, bufB, 768, 0);
        gemm_f32<<<dim3(256 / 64, ch / 64), dim3(256), 0, stream>>>(
            bufB, 768, 772, 768, coords, base, iw1, ib1, bufA, 256, 1);
        ln_kernel<<<dim3(ch), dim3(256), 0, stream>>>(bufA, lng, lnb);
        gemm_f32<<<dim3(256 / 64, ch / 64), dim3(256), 0, stream>>>(
            bufA, 256, 256, 256, nullptr, 0, iw2, ib2, bufB, 256, 1);
        imp_kernel<<<dim3(ch), dim3(256), 0, stream>>>(bufB, iw3, ib3, noise, lt, pert, base);
    }

    // ---- selection + KNN ----
    topk_kernel<<<dim3(BATCH), dim3(256), 0, stream>>>(pert, coords, centf);
    knn_kernel<<<dim3(BATCH * MT), dim3(256), 0, stream>>>(coords, centf, knn);

    // ---- recompute pf for the 16384 gathered neighbor rows (chunked), pool ----
    const int NBR = BATCH * MT * KNN;   // 16384
    for (int rc = 0; rc < NBR / ch; ++rc) {
        l1_kernel<<<dim3(ch), dim3(256), 0, stream>>>(feats, w1, b1, bufA, 0, knn + (size_t)rc * ch);
        gemm_f32<<<dim3(512 / 64, ch / 64), dim3(256), 0, stream>>>(
            bufA, 256, 256, 256, nullptr, 0, w2, b2, bufB, 512, 1);
        gemm_f32<<<dim3(768 / 64, ch / 64), dim3(256), 0, stream>>>(
            bufB, 512, 512, 512, nullptr, 0, w3, b3, bufA, 768, 1);
        gemm_f32<<<dim3(768 / 64, ch / 64), dim3(256), 0, stream>>>(
            bufA, 768, 768, 768, nullptr, 0, w4, b4, bufB, 768, 0);
        pool_kernel<<<dim3(ch / KNN), dim3(256), 0, stream>>>(
            bufB, pooled + (size_t)rc * (ch / KNN) * TOKD);
    }

    // ---- token MLP (1024x768) + emit ----
    if (ch >= 1024) {
        // batched: t1 = bufA (786,432 <= ch*768), tokf = bufB
        float* t1 = bufA, *tokf = bufB;
        gemm_f32<<<dim3(768 / 64, 1024 / 64), dim3(256), 0, stream>>>(
            pooled, 768, 768, 768, nullptr, 0, nw1, nb1, t1, 768, 1);
        gemm_f32<<<dim3(768 / 64, 1024 / 64), dim3(256), 0, stream>>>(
            t1, 768, 768, 768, nullptr, 0, nw2, nb2, tokf, 768, 0);
        for (int e = 0; e < BATCH; ++e)
            emit_kernel<<<dim3(1), dim3(256), 0, stream>>>(
                centf, tokf + (size_t)e * MT * TOKD, e, (float*)d_out, (long)out_size);
    } else {
        // per-event fallback for small ws (128*768 <= ch*768 for ch>=128)
        for (int e = 0; e < BATCH; ++e) {
            gemm_f32<<<dim3(768 / 64, MT / 64), dim3(256), 0, stream>>>(
                pooled + (size_t)e * MT * TOKD, 768, 768, 768, nullptr, 0,
                nw1, nb1, bufA, 768, 1);
            gemm_f32<<<dim3(768 / 64, MT / 64), dim3(256), 0, stream>>>(
                bufA, 768, 768, 768, nullptr, 0, nw2, nb2, bufB, 768, 0);
            emit_kernel<<<dim3(1), dim3(256), 0, stream>>>(
                centf, bufB, e, (float*)d_out, (long)out_size);
        }
    }
}